// Round 1
// baseline (577.545 us; speedup 1.0000x reference)
//
#include <hip/hip_runtime.h>

typedef __bf16 bf16;
typedef __attribute__((ext_vector_type(8))) __bf16 bf16x8;
typedef __attribute__((ext_vector_type(4))) float f32x4;
typedef __attribute__((ext_vector_type(4))) unsigned int u32x4;

// ---- constants for this problem ----
#define BB 2
#define TT 2048
#define DD 2048
#define HH 16
#define HKV 4
#define DHD 128
#define NQKV 3072   // H*DH + 2*HKV*DH
#define NQK 2560    // q+k features (stored to Craw)

__device__ __forceinline__ void gl_lds16(const bf16* g, bf16* l) {
    __builtin_amdgcn_global_load_lds(
        (const __attribute__((address_space(1))) void*)g,
        (__attribute__((address_space(3))) void*)l, 16, 0, 0);
}

// ---------------- fp32 -> bf16 convert ----------------
__global__ void cvt_bf16(const float* __restrict__ src, bf16* __restrict__ dst, int n8) {
    int i = blockIdx.x * 256 + threadIdx.x;
    if (i >= n8) return;
    float4 a = ((const float4*)src)[i * 2];
    float4 b = ((const float4*)src)[i * 2 + 1];
    bf16x8 v;
    v[0] = (bf16)a.x; v[1] = (bf16)a.y; v[2] = (bf16)a.z; v[3] = (bf16)a.w;
    v[4] = (bf16)b.x; v[5] = (bf16)b.y; v[6] = (bf16)b.z; v[7] = (bf16)b.w;
    *(bf16x8*)(dst + (size_t)i * 8) = v;
}

// ---------------- GEMM: C = A(MxK) * Bw(NxK)^T, bf16 in, fp32 acc ----------------
// MODE 0: plain store fp32 Cout (ld = N)
// MODE 1: QKV epilogue: n<2560 -> Craw (ld=2560); n>=2560 -> v-mix -> vT bf16 (B,HKV,DH,T)
template <int MODE>
__global__ void gemm_bt(const bf16* __restrict__ A, const bf16* __restrict__ Bw,
                        int M, int N, int K,
                        float* __restrict__ Cout,
                        bf16* __restrict__ vT,
                        const float* __restrict__ v1,
                        const float* __restrict__ lamp) {
    __shared__ bf16 As[128 * 32];
    __shared__ bf16 Bs[128 * 32];
    const int tid = threadIdx.x;
    const int w = tid >> 6, lane = tid & 63;
    const int l15 = lane & 15, quad = lane >> 4;
    const int m0 = blockIdx.y * 128, n0 = blockIdx.x * 128;
    const int wm = (w & 1) * 64, wn = (w >> 1) * 64;

    f32x4 acc[4][4] = {};

    const int lrow = lane >> 2;          // 0..15 within chunk
    const int lcol = (lane & 3) * 8;     // bf16 elems

    for (int k0 = 0; k0 < K; k0 += 32) {
#pragma unroll
        for (int i = 0; i < 2; i++) {
            int c = w * 2 + i;
            int row = c * 16 + lrow;
            gl_lds16(A + (size_t)(m0 + row) * K + k0 + lcol, As + c * 512);
        }
#pragma unroll
        for (int i = 0; i < 2; i++) {
            int c = w * 2 + i;
            int row = c * 16 + lrow;
            gl_lds16(Bw + (size_t)(n0 + row) * K + k0 + lcol, Bs + c * 512);
        }
        __syncthreads();
        bf16x8 af[4], bfr[4];
#pragma unroll
        for (int mi = 0; mi < 4; mi++)
            af[mi] = *(const bf16x8*)(As + (wm + mi * 16 + l15) * 32 + quad * 8);
#pragma unroll
        for (int ni = 0; ni < 4; ni++)
            bfr[ni] = *(const bf16x8*)(Bs + (wn + ni * 16 + l15) * 32 + quad * 8);
#pragma unroll
        for (int mi = 0; mi < 4; mi++)
#pragma unroll
            for (int ni = 0; ni < 4; ni++)
                acc[mi][ni] = __builtin_amdgcn_mfma_f32_16x16x32_bf16(af[mi], bfr[ni], acc[mi][ni], 0, 0, 0);
        __syncthreads();
    }

    float lam = 0.f;
    if constexpr (MODE == 1) lam = lamp[0];

#pragma unroll
    for (int mi = 0; mi < 4; mi++)
#pragma unroll
        for (int ni = 0; ni < 4; ni++)
#pragma unroll
            for (int r = 0; r < 4; r++) {
                int m = m0 + wm + mi * 16 + quad * 4 + r;
                int n = n0 + wn + ni * 16 + l15;
                float val = acc[mi][ni][r];
                if constexpr (MODE == 0) {
                    Cout[(size_t)m * N + n] = val;
                } else {
                    if (n < NQK) {
                        Cout[(size_t)m * NQK + n] = val;
                    } else {
                        int f2 = n - NQK;
                        int hk = f2 >> 7, d = f2 & 127;
                        int b = m >> 11, t = m & (TT - 1);
                        size_t i1 = ((size_t)(b * HKV + hk) * TT + t) * DHD + d;
                        float vm = val + lam * (v1[i1] - val);
                        vT[((size_t)(b * HKV + hk) * DHD + d) * TT + t] = (bf16)vm;
                    }
                }
            }
}

// ---------------- RMSNorm + ortho RoPE, wave per (token, head) ----------------
__global__ void rmsrope(const float* __restrict__ Craw, const float* __restrict__ cosb,
                        const float* __restrict__ sinb, bf16* __restrict__ qb,
                        bf16* __restrict__ kb) {
    int gw = blockIdx.x * 4 + (threadIdx.x >> 6);
    int lane = threadIdx.x & 63;
    int token = gw / 20, hh = gw % 20;  // 0..15 q heads, 16..19 k heads
    int b = token >> 11, t = token & (TT - 1);
    int off = (hh < HH) ? hh * DHD : (HH * DHD + (hh - HH) * DHD);
    const float* src = Craw + (size_t)token * NQK + off;
    float2 xv = *(const float2*)(src + lane * 2);
    float x0 = xv.x, x1 = xv.y;
    float ss = x0 * x0 + x1 * x1;
#pragma unroll
    for (int m = 1; m < 64; m <<= 1) ss += __shfl_xor(ss, m);
    float r = rsqrtf(ss * (1.f / 128.f) + 1e-6f);
    x0 *= r; x1 *= r;
    float c = cosb[t * 64 + lane], s = sinb[t * 64 + lane];
    float y0 = x0 * c - x1 * s;
    float y1 = x1 * c + x0 * s;
    bf16* dst = (hh < HH) ? (qb + ((size_t)(b * HH + hh) * TT + t) * DHD)
                          : (kb + ((size_t)(b * HKV + (hh - HH)) * TT + t) * DHD);
    dst[lane] = (bf16)y0;
    dst[64 + lane] = (bf16)y1;
}

// ---------------- gates = sigmoid(x[:, :16] @ gate_w^T) ----------------
__global__ void gatesk(const float* __restrict__ x, const float* __restrict__ gw,
                       float* __restrict__ gates) {
    __shared__ float gws[256];
    gws[threadIdx.x] = gw[threadIdx.x];
    __syncthreads();
    int idx = blockIdx.x * 256 + threadIdx.x;
    int h = idx & 15, token = idx >> 4;
    const float* xr = x + (size_t)token * DD;
    float z = 0.f;
#pragma unroll
    for (int j = 0; j < 16; j++) z += xr[j] * gws[h * 16 + j];
    gates[idx] = 1.f / (1.f + __expf(-z));
}

// ---------------- flash attention, block = 64 q rows, k-tiles of 64 ----------------
__global__ __launch_bounds__(256) void fattn(const bf16* __restrict__ qb,
                                             const bf16* __restrict__ kb,
                                             const bf16* __restrict__ vt,
                                             const float* __restrict__ gates,
                                             bf16* __restrict__ yb) {
    __shared__ bf16 Qs[64 * 136];
    __shared__ bf16 Ks[64 * 136];
    __shared__ bf16 VTs[128 * 72];
    __shared__ bf16 Ps[4 * 16 * 72];

    int bid = blockIdx.x;
    int qt = 31 - (bid & 31);     // big tiles dispatched first
    int h = (bid >> 5) & 15;
    int b = bid >> 9;
    int hk = h >> 2;
    int tid = threadIdx.x, w = tid >> 6, lane = tid & 63;
    int l15 = lane & 15, quad = lane >> 4;

    const bf16* qbase = qb + ((size_t)(b * HH + h) * TT + qt * 64) * DHD;
    const bf16* kbase = kb + ((size_t)(b * HKV + hk) * TT) * DHD;
    const bf16* vtbase = vt + ((size_t)(b * HKV + hk) * DHD) * TT;

    // stage Q once: 64 rows x 128 -> padded 136
#pragma unroll
    for (int i = 0; i < 4; i++) {
        int cid = tid + i * 256;
        int row = cid >> 4, c16 = cid & 15;
        *(u32x4*)(Qs + row * 136 + c16 * 8) = *(const u32x4*)(qbase + row * DHD + c16 * 8);
    }
    __syncthreads();
    bf16x8 aq[4];
#pragma unroll
    for (int kc = 0; kc < 4; kc++)
        aq[kc] = *(const bf16x8*)(Qs + (w * 16 + l15) * 136 + kc * 32 + quad * 8);

    f32x4 Oacc[8] = {};
    float mrow[4], lrow[4];
#pragma unroll
    for (int r = 0; r < 4; r++) { mrow[r] = -INFINITY; lrow[r] = 0.f; }
    const float scale = 0.08838834764831845f;  // 1/sqrt(128)

    for (int kt = 0; kt <= qt; kt++) {
        // stage K (64x128 -> 136) and VT (128x64 -> 72)
#pragma unroll
        for (int i = 0; i < 4; i++) {
            int cid = tid + i * 256;
            int row = cid >> 4, c16 = cid & 15;
            *(u32x4*)(Ks + row * 136 + c16 * 8) =
                *(const u32x4*)(kbase + (size_t)(kt * 64 + row) * DHD + c16 * 8);
        }
#pragma unroll
        for (int i = 0; i < 4; i++) {
            int cid = tid + i * 256;
            int d = cid >> 3, c8 = cid & 7;
            *(u32x4*)(VTs + d * 72 + c8 * 8) =
                *(const u32x4*)(vtbase + (size_t)d * TT + kt * 64 + c8 * 8);
        }
        __syncthreads();

        // S = Q K^T : wave's 16 q rows x 64 k cols
        f32x4 sacc[4];
#pragma unroll
        for (int ni = 0; ni < 4; ni++) {
            f32x4 z = {};
#pragma unroll
            for (int kc = 0; kc < 4; kc++) {
                bf16x8 bk = *(const bf16x8*)(Ks + (ni * 16 + l15) * 136 + kc * 32 + quad * 8);
                z = __builtin_amdgcn_mfma_f32_16x16x32_bf16(aq[kc], bk, z, 0, 0, 0);
            }
            sacc[ni] = z;
        }

        bool diag = (kt == qt);
        float p[4][4];
        float alpha[4];
#pragma unroll
        for (int r = 0; r < 4; r++) {
            int qg = qt * 64 + w * 16 + quad * 4 + r;
            float sv[4];
            float mx = -INFINITY;
#pragma unroll
            for (int ni = 0; ni < 4; ni++) {
                float sc = sacc[ni][r] * scale;
                int kg = kt * 64 + ni * 16 + l15;
                if (diag && kg > qg) sc = -INFINITY;
                sv[ni] = sc;
                mx = fmaxf(mx, sc);
            }
#pragma unroll
            for (int m = 1; m < 16; m <<= 1) mx = fmaxf(mx, __shfl_xor(mx, m));
            float mnew = fmaxf(mrow[r], mx);
            float a = __expf(mrow[r] - mnew);
            alpha[r] = a;
            float rs = 0.f;
#pragma unroll
            for (int ni = 0; ni < 4; ni++) {
                float pe = __expf(sv[ni] - mnew);
                p[r][ni] = pe;
                rs += pe;
            }
#pragma unroll
            for (int m = 1; m < 16; m <<= 1) rs += __shfl_xor(rs, m);
            lrow[r] = lrow[r] * a + rs;
            mrow[r] = mnew;
        }
#pragma unroll
        for (int dn = 0; dn < 8; dn++)
#pragma unroll
            for (int r = 0; r < 4; r++) Oacc[dn][r] *= alpha[r];

        // P: C-layout regs -> LDS (per-wave region) for A-layout reads
        bf16* pw = Ps + w * 16 * 72;
#pragma unroll
        for (int r = 0; r < 4; r++)
#pragma unroll
            for (int ni = 0; ni < 4; ni++)
                pw[(quad * 4 + r) * 72 + ni * 16 + l15] = (bf16)p[r][ni];

        // O += P * V
#pragma unroll
        for (int kc2 = 0; kc2 < 2; kc2++) {
            bf16x8 ap = *(const bf16x8*)(pw + l15 * 72 + kc2 * 32 + quad * 8);
#pragma unroll
            for (int dn = 0; dn < 8; dn++) {
                bf16x8 bv = *(const bf16x8*)(VTs + (dn * 16 + l15) * 72 + kc2 * 32 + quad * 8);
                Oacc[dn] = __builtin_amdgcn_mfma_f32_16x16x32_bf16(ap, bv, Oacc[dn], 0, 0, 0);
            }
        }
        __syncthreads();
    }

    // epilogue: O/l * gate -> yb (B,T,H*DH) bf16
#pragma unroll
    for (int r = 0; r < 4; r++) {
        int qg = qt * 64 + w * 16 + quad * 4 + r;
        float inv = 1.f / lrow[r];
        float g = gates[((size_t)b * TT + qg) * HH + h];
        float gi = inv * g;
#pragma unroll
        for (int dn = 0; dn < 8; dn++) {
            float y = Oacc[dn][r] * gi;
            yb[((size_t)(b * TT + qg) * HH + h) * DHD + dn * 16 + l15] = (bf16)y;
        }
    }
}

extern "C" void kernel_launch(void* const* d_in, const int* in_sizes, int n_in,
                              void* d_out, int out_size, void* d_ws, size_t ws_size,
                              hipStream_t stream) {
    const float* x    = (const float*)d_in[0];
    const float* cosb = (const float*)d_in[2];
    const float* sinb = (const float*)d_in[3];
    const float* v1   = (const float*)d_in[4];
    const float* Wq   = (const float*)d_in[5];
    const float* Wk   = (const float*)d_in[6];
    const float* Wv   = (const float*)d_in[7];
    const float* Wo   = (const float*)d_in[8];
    const float* gw   = (const float*)d_in[9];
    const float* lam  = (const float*)d_in[10];
    float* out = (float*)d_out;

    char* ws = (char*)d_ws;
    bf16* xb     = (bf16*)(ws);                   // 16,777,216 B (reused later by yb)
    bf16* wqkvb  = (bf16*)(ws + 16777216);        // 12,582,912
    bf16* wob    = (bf16*)(ws + 29360128);        //  8,388,608
    float* Craw  = (float*)(ws + 37748736);       // 41,943,040 (4096 x 2560 fp32)
    bf16* qb     = (bf16*)(ws + 79691776);        // 16,777,216
    bf16* kb     = (bf16*)(ws + 96468992);        //  4,194,304
    bf16* vtb    = (bf16*)(ws + 100663296);       //  4,194,304
    float* gts   = (float*)(ws + 104857600);      //    262,144
    bf16* yb     = xb;                            // alias: xb dead after QKV GEMM

    // converts
    cvt_bf16<<<4096, 256, 0, stream>>>(x, xb, 1048576);
    cvt_bf16<<<2048, 256, 0, stream>>>(Wq, wqkvb, 524288);
    cvt_bf16<<<512, 256, 0, stream>>>(Wk, wqkvb + 4194304, 131072);
    cvt_bf16<<<512, 256, 0, stream>>>(Wv, wqkvb + 5242880, 131072);
    cvt_bf16<<<2048, 256, 0, stream>>>(Wo, wob, 524288);

    // QKV projection (writes Craw for q/k, mixed+transposed bf16 V)
    gemm_bt<1><<<dim3(24, 32), 256, 0, stream>>>(xb, wqkvb, 4096, NQKV, 2048,
                                                 Craw, vtb, v1, lam);
    // rmsnorm + rope -> bf16 q/k
    rmsrope<<<20480, 256, 0, stream>>>(Craw, cosb, sinb, qb, kb);
    // gates
    gatesk<<<256, 256, 0, stream>>>(x, gw, gts);
    // flash attention (writes gated y, token-major bf16) -- yb aliases xb
    fattn<<<1024, 256, 0, stream>>>(qb, kb, vtb, gts, yb);
    // output projection
    gemm_bt<0><<<dim3(16, 32), 256, 0, stream>>>(yb, wob, 4096, 2048, 2048,
                                                 out, nullptr, nullptr, nullptr);
    // v1 passthrough (second tuple output)
    hipMemcpyAsync(out + 8388608, v1, (size_t)2097152 * sizeof(float),
                   hipMemcpyDeviceToDevice, stream);
}

// Round 2
// 426.879 us; speedup vs baseline: 1.3529x; 1.3529x over previous
//
#include <hip/hip_runtime.h>

typedef __bf16 bf16;
typedef __attribute__((ext_vector_type(8))) __bf16 bf16x8;
typedef __attribute__((ext_vector_type(4))) float f32x4;
typedef __attribute__((ext_vector_type(4))) unsigned int u32x4;

// ---- constants for this problem ----
#define BB 2
#define TT 2048
#define DD 2048
#define HH 16
#define HKV 4
#define DHD 128
#define NQKV 3072   // H*DH + 2*HKV*DH
#define NQK 2560    // q+k features (stored to Craw)

__device__ __forceinline__ void gl_lds16(const bf16* g, bf16* l) {
    __builtin_amdgcn_global_load_lds(
        (const __attribute__((address_space(1))) void*)g,
        (__attribute__((address_space(3))) void*)l, 16, 0, 0);
}

// ---------------- fp32 -> bf16 convert ----------------
__global__ void cvt_bf16(const float* __restrict__ src, bf16* __restrict__ dst, int n8) {
    int i = blockIdx.x * 256 + threadIdx.x;
    if (i >= n8) return;
    float4 a = ((const float4*)src)[i * 2];
    float4 b = ((const float4*)src)[i * 2 + 1];
    bf16x8 v;
    v[0] = (bf16)a.x; v[1] = (bf16)a.y; v[2] = (bf16)a.z; v[3] = (bf16)a.w;
    v[4] = (bf16)b.x; v[5] = (bf16)b.y; v[6] = (bf16)b.z; v[7] = (bf16)b.w;
    *(bf16x8*)(dst + (size_t)i * 8) = v;
}

// ---------------- GEMM: C = A(MxK) * Bw(NxK)^T, bf16 in, fp32 acc ----------------
// MODE 0: plain store fp32 Cout (ld = N)
// MODE 1: QKV epilogue: n<2560 -> Craw (ld=2560); n>=2560 -> v-mix -> vT bf16 (B,HKV,DH,T)
template <int MODE>
__global__ void gemm_bt(const bf16* __restrict__ A, const bf16* __restrict__ Bw,
                        int M, int N, int K,
                        float* __restrict__ Cout,
                        bf16* __restrict__ vT,
                        const float* __restrict__ v1,
                        const float* __restrict__ lamp) {
    __shared__ bf16 As[128 * 32];
    __shared__ bf16 Bs[128 * 32];
    const int tid = threadIdx.x;
    const int w = tid >> 6, lane = tid & 63;
    const int l15 = lane & 15, quad = lane >> 4;
    const int m0 = blockIdx.y * 128, n0 = blockIdx.x * 128;
    const int wm = (w & 1) * 64, wn = (w >> 1) * 64;

    f32x4 acc[4][4] = {};

    const int lrow = lane >> 2;          // 0..15 within chunk
    const int lcol = (lane & 3) * 8;     // bf16 elems

    for (int k0 = 0; k0 < K; k0 += 32) {
#pragma unroll
        for (int i = 0; i < 2; i++) {
            int c = w * 2 + i;
            int row = c * 16 + lrow;
            gl_lds16(A + (size_t)(m0 + row) * K + k0 + lcol, As + c * 512);
        }
#pragma unroll
        for (int i = 0; i < 2; i++) {
            int c = w * 2 + i;
            int row = c * 16 + lrow;
            gl_lds16(Bw + (size_t)(n0 + row) * K + k0 + lcol, Bs + c * 512);
        }
        __syncthreads();
        bf16x8 af[4], bfr[4];
#pragma unroll
        for (int mi = 0; mi < 4; mi++)
            af[mi] = *(const bf16x8*)(As + (wm + mi * 16 + l15) * 32 + quad * 8);
#pragma unroll
        for (int ni = 0; ni < 4; ni++)
            bfr[ni] = *(const bf16x8*)(Bs + (wn + ni * 16 + l15) * 32 + quad * 8);
#pragma unroll
        for (int mi = 0; mi < 4; mi++)
#pragma unroll
            for (int ni = 0; ni < 4; ni++)
                acc[mi][ni] = __builtin_amdgcn_mfma_f32_16x16x32_bf16(af[mi], bfr[ni], acc[mi][ni], 0, 0, 0);
        __syncthreads();
    }

    float lam = 0.f;
    if constexpr (MODE == 1) lam = lamp[0];

#pragma unroll
    for (int mi = 0; mi < 4; mi++)
#pragma unroll
        for (int ni = 0; ni < 4; ni++)
#pragma unroll
            for (int r = 0; r < 4; r++) {
                int m = m0 + wm + mi * 16 + quad * 4 + r;
                int n = n0 + wn + ni * 16 + l15;
                float val = acc[mi][ni][r];
                if constexpr (MODE == 0) {
                    Cout[(size_t)m * N + n] = val;
                } else {
                    if (n < NQK) {
                        Cout[(size_t)m * NQK + n] = val;
                    } else {
                        int f2 = n - NQK;
                        int hk = f2 >> 7, d = f2 & 127;
                        int b = m >> 11, t = m & (TT - 1);
                        size_t i1 = ((size_t)(b * HKV + hk) * TT + t) * DHD + d;
                        float vm = val + lam * (v1[i1] - val);
                        vT[((size_t)(b * HKV + hk) * DHD + d) * TT + t] = (bf16)vm;
                    }
                }
            }
}

// ---------------- RMSNorm + ortho RoPE, wave per (token, head) ----------------
__global__ void rmsrope(const float* __restrict__ Craw, const float* __restrict__ cosb,
                        const float* __restrict__ sinb, bf16* __restrict__ qb,
                        bf16* __restrict__ kb) {
    int gw = blockIdx.x * 4 + (threadIdx.x >> 6);
    int lane = threadIdx.x & 63;
    int token = gw / 20, hh = gw % 20;  // 0..15 q heads, 16..19 k heads
    int b = token >> 11, t = token & (TT - 1);
    int off = (hh < HH) ? hh * DHD : (HH * DHD + (hh - HH) * DHD);
    const float* src = Craw + (size_t)token * NQK + off;
    float2 xv = *(const float2*)(src + lane * 2);
    float x0 = xv.x, x1 = xv.y;
    float ss = x0 * x0 + x1 * x1;
#pragma unroll
    for (int m = 1; m < 64; m <<= 1) ss += __shfl_xor(ss, m);
    float r = rsqrtf(ss * (1.f / 128.f) + 1e-6f);
    x0 *= r; x1 *= r;
    float c = cosb[t * 64 + lane], s = sinb[t * 64 + lane];
    float y0 = x0 * c - x1 * s;
    float y1 = x1 * c + x0 * s;
    bf16* dst = (hh < HH) ? (qb + ((size_t)(b * HH + hh) * TT + t) * DHD)
                          : (kb + ((size_t)(b * HKV + (hh - HH)) * TT + t) * DHD);
    dst[lane] = (bf16)y0;
    dst[64 + lane] = (bf16)y1;
}

// ---------------- gates = sigmoid(x[:, :16] @ gate_w^T) ----------------
__global__ void gatesk(const float* __restrict__ x, const float* __restrict__ gw,
                       float* __restrict__ gates) {
    __shared__ float gws[256];
    gws[threadIdx.x] = gw[threadIdx.x];
    __syncthreads();
    int idx = blockIdx.x * 256 + threadIdx.x;
    int h = idx & 15, token = idx >> 4;
    const float* xr = x + (size_t)token * DD;
    float z = 0.f;
#pragma unroll
    for (int j = 0; j < 16; j++) z += xr[j] * gws[h * 16 + j];
    gates[idx] = 1.f / (1.f + __expf(-z));
}

// ---------------- flash attention, paired q-tiles (j, 31-j), dbuf global_load_lds ----------------
__global__ __launch_bounds__(256, 2) void fattn(const bf16* __restrict__ qbuf,
                                                const bf16* __restrict__ kbuf,
                                                const bf16* __restrict__ vt,
                                                const float* __restrict__ gates,
                                                bf16* __restrict__ yb) {
    // K tile: [buf][kc(4) of 32 d][64 rows][32 d]  (8192 bf16 per buf)
    // VT tile:[buf][kc2(2) of 32 t][128 d][32 t]   (8192 bf16 per buf)
    __shared__ bf16 Ks[2][4][64 * 32];
    __shared__ bf16 VTs[2][2][128 * 32];
    __shared__ bf16 Ps[4][16 * 72];

    const int bid = blockIdx.x;          // 512 blocks
    const int j = bid & 15;
    const int bh = bid >> 4;             // 0..31
    const int h = bh & 15, b = bh >> 4;
    const int hk = h >> 2;
    const int qa = 31 - j;               // big tile
    const int qbt = j;                   // small tile
    const int tid = threadIdx.x, w = tid >> 6, lane = tid & 63;
    const int l15 = lane & 15, quad = lane >> 4;

    const bf16* qbase = qbuf + ((size_t)(b * HH + h) * TT) * DHD;
    const bf16* kbase = kbuf + ((size_t)(b * HKV + hk) * TT) * DHD;
    const bf16* vtbase = vt + ((size_t)(b * HKV + hk) * DHD) * TT;

    // Q fragments direct from global (read once)
    bf16x8 aqA[4], aqB[4];
#pragma unroll
    for (int kc = 0; kc < 4; kc++) {
        aqA[kc] = *(const bf16x8*)(qbase + (size_t)(qa * 64 + w * 16 + l15) * DHD + kc * 32 + quad * 8);
        aqB[kc] = *(const bf16x8*)(qbase + (size_t)(qbt * 64 + w * 16 + l15) * DHD + kc * 32 + quad * 8);
    }

    const int srow = lane >> 2;          // 0..15
    const int scg = (lane & 3) * 8;      // 0,8,16,24 (elems)

    auto stage = [&](int kt, int buf) {
#pragma unroll
        for (int i = 0; i < 4; i++) {
            // K: chunk kc=i, rows w*16..w*16+15
            gl_lds16(kbase + (size_t)(kt * 64 + w * 16 + srow) * DHD + i * 32 + scg,
                     &Ks[buf][i][w * 512]);
            // VT: chunk kc2=i>>1, d rows (i&1)*64 + w*16 ..
            int d = (i & 1) * 64 + w * 16 + srow;
            gl_lds16(vtbase + (size_t)d * TT + kt * 64 + (i >> 1) * 32 + scg,
                     &VTs[buf][i >> 1][((i & 1) * 64 + w * 16) * 32]);
        }
    };

    stage(0, 0);

    f32x4 OA[8] = {}, OB[8] = {};
    float mA[4], lA[4], mB[4], lB[4];
#pragma unroll
    for (int r = 0; r < 4; r++) { mA[r] = -INFINITY; lA[r] = 0.f; mB[r] = -INFINITY; lB[r] = 0.f; }
    const float scale = 0.08838834764831845f;  // 1/sqrt(128)
    bf16* pw = Ps[w];

    auto attn_step = [&](const bf16x8* aq, f32x4* Oc, float* mr, float* lr,
                         int cur, int kt, int qt) {
        // S = Q K^T : wave's 16 q rows x 64 k cols
        f32x4 sacc[4];
#pragma unroll
        for (int ni = 0; ni < 4; ni++) {
            f32x4 z = {};
#pragma unroll
            for (int kc = 0; kc < 4; kc++) {
                bf16x8 bk = *(const bf16x8*)(&Ks[cur][kc][(ni * 16 + l15) * 32 + quad * 8]);
                z = __builtin_amdgcn_mfma_f32_16x16x32_bf16(aq[kc], bk, z, 0, 0, 0);
            }
            sacc[ni] = z;
        }

        const bool diag = (kt == qt);
        float p[4][4];
        float alpha[4];
#pragma unroll
        for (int r = 0; r < 4; r++) {
            int qg = qt * 64 + w * 16 + quad * 4 + r;
            float sv[4];
            float mx = -INFINITY;
#pragma unroll
            for (int ni = 0; ni < 4; ni++) {
                float sc = sacc[ni][r] * scale;
                int kg = kt * 64 + ni * 16 + l15;
                if (diag && kg > qg) sc = -INFINITY;
                sv[ni] = sc;
                mx = fmaxf(mx, sc);
            }
#pragma unroll
            for (int m = 1; m < 16; m <<= 1) mx = fmaxf(mx, __shfl_xor(mx, m));
            float mnew = fmaxf(mr[r], mx);
            float a = __expf(mr[r] - mnew);
            alpha[r] = a;
            float rs = 0.f;
#pragma unroll
            for (int ni = 0; ni < 4; ni++) {
                float pe = __expf(sv[ni] - mnew);
                p[r][ni] = pe;
                rs += pe;
            }
#pragma unroll
            for (int m = 1; m < 16; m <<= 1) rs += __shfl_xor(rs, m);
            lr[r] = lr[r] * a + rs;
            mr[r] = mnew;
        }
#pragma unroll
        for (int dn = 0; dn < 8; dn++)
#pragma unroll
            for (int r = 0; r < 4; r++) Oc[dn][r] *= alpha[r];

        // P: C-layout regs -> per-wave LDS region -> A-layout reads
#pragma unroll
        for (int r = 0; r < 4; r++)
#pragma unroll
            for (int ni = 0; ni < 4; ni++)
                pw[(quad * 4 + r) * 72 + ni * 16 + l15] = (bf16)p[r][ni];

#pragma unroll
        for (int kc2 = 0; kc2 < 2; kc2++) {
            bf16x8 ap = *(const bf16x8*)(pw + l15 * 72 + kc2 * 32 + quad * 8);
#pragma unroll
            for (int dn = 0; dn < 8; dn++) {
                bf16x8 bv = *(const bf16x8*)(&VTs[cur][kc2][(dn * 16 + l15) * 32 + quad * 8]);
                Oc[dn] = __builtin_amdgcn_mfma_f32_16x16x32_bf16(ap, bv, Oc[dn], 0, 0, 0);
            }
        }
    };

    for (int kt = 0; kt <= qa; kt++) {
        int cur = kt & 1;
        __syncthreads();                 // drains loads for buf `cur` (issued one iter ago)
        if (kt < qa) stage(kt + 1, cur ^ 1);   // prefetch; drained at NEXT barrier
        attn_step(aqA, OA, mA, lA, cur, kt, qa);
        if (kt <= qbt) attn_step(aqB, OB, mB, lB, cur, kt, qbt);
    }

    // epilogue: O/l * gate -> yb (B,T,H*DH) bf16
    auto epi = [&](const f32x4* Oc, const float* lr, int qt) {
#pragma unroll
        for (int r = 0; r < 4; r++) {
            int qg = qt * 64 + w * 16 + quad * 4 + r;
            float inv = 1.f / lr[r];
            float g = gates[((size_t)b * TT + qg) * HH + h];
            float gi = inv * g;
#pragma unroll
            for (int dn = 0; dn < 8; dn++) {
                float y = Oc[dn][r] * gi;
                yb[((size_t)(b * TT + qg) * HH + h) * DHD + dn * 16 + l15] = (bf16)y;
            }
        }
    };
    epi(OA, lA, qa);
    epi(OB, lB, qbt);
}

extern "C" void kernel_launch(void* const* d_in, const int* in_sizes, int n_in,
                              void* d_out, int out_size, void* d_ws, size_t ws_size,
                              hipStream_t stream) {
    const float* x    = (const float*)d_in[0];
    const float* cosb = (const float*)d_in[2];
    const float* sinb = (const float*)d_in[3];
    const float* v1   = (const float*)d_in[4];
    const float* Wq   = (const float*)d_in[5];
    const float* Wk   = (const float*)d_in[6];
    const float* Wv   = (const float*)d_in[7];
    const float* Wo   = (const float*)d_in[8];
    const float* gw   = (const float*)d_in[9];
    const float* lam  = (const float*)d_in[10];
    float* out = (float*)d_out;

    char* ws = (char*)d_ws;
    bf16* xb     = (bf16*)(ws);                   // 16,777,216 B (reused later by yb)
    bf16* wqkvb  = (bf16*)(ws + 16777216);        // 12,582,912
    bf16* wob    = (bf16*)(ws + 29360128);        //  8,388,608
    float* Craw  = (float*)(ws + 37748736);       // 41,943,040 (4096 x 2560 fp32)
    bf16* qb     = (bf16*)(ws + 79691776);        // 16,777,216
    bf16* kb     = (bf16*)(ws + 96468992);        //  4,194,304
    bf16* vtb    = (bf16*)(ws + 100663296);       //  4,194,304
    float* gts   = (float*)(ws + 104857600);      //    262,144
    bf16* yb     = xb;                            // alias: xb dead after QKV GEMM

    // converts
    cvt_bf16<<<4096, 256, 0, stream>>>(x, xb, 1048576);
    cvt_bf16<<<2048, 256, 0, stream>>>(Wq, wqkvb, 524288);
    cvt_bf16<<<512, 256, 0, stream>>>(Wk, wqkvb + 4194304, 131072);
    cvt_bf16<<<512, 256, 0, stream>>>(Wv, wqkvb + 5242880, 131072);
    cvt_bf16<<<2048, 256, 0, stream>>>(Wo, wob, 524288);

    // QKV projection (writes Craw for q/k, mixed+transposed bf16 V)
    gemm_bt<1><<<dim3(24, 32), 256, 0, stream>>>(xb, wqkvb, 4096, NQKV, 2048,
                                                 Craw, vtb, v1, lam);
    // rmsnorm + rope -> bf16 q/k
    rmsrope<<<20480, 256, 0, stream>>>(Craw, cosb, sinb, qb, kb);
    // gates
    gatesk<<<256, 256, 0, stream>>>(x, gw, gts);
    // flash attention (paired q-tiles, dbuf prefetch) -- yb aliases xb
    fattn<<<512, 256, 0, stream>>>(qb, kb, vtb, gts, yb);
    // output projection
    gemm_bt<0><<<dim3(16, 32), 256, 0, stream>>>(yb, wob, 4096, 2048, 2048,
                                                 out, nullptr, nullptr, nullptr);
    // v1 passthrough (second tuple output)
    hipMemcpyAsync(out + 8388608, v1, (size_t)2097152 * sizeof(float),
                   hipMemcpyDeviceToDevice, stream);
}